// Round 3
// baseline (618.016 us; speedup 1.0000x reference)
//
#include <hip/hip_runtime.h>
#include <stdint.h>
#include <math.h>

// Problem constants
#define NROWS 2048
#define SEQ   128
#define EMB   512
#define HID   1024   // output cols per row

// ---------------------------------------------------------------------------
// threefry2x32 (JAX PRNG), exact
// ---------------------------------------------------------------------------
struct U2 { uint32_t x, y; };

__device__ __forceinline__ uint32_t rotl32(uint32_t v, int r) {
  return (v << r) | (v >> (32 - r));
}

__device__ __forceinline__ U2 tf2x32(U2 key, uint32_t x0, uint32_t x1) {
  uint32_t ks0 = key.x, ks1 = key.y;
  uint32_t ks2 = ks0 ^ ks1 ^ 0x1BD11BDAu;
  x0 += ks0; x1 += ks1;
  x0 += x1; x1 = rotl32(x1, 13); x1 ^= x0;
  x0 += x1; x1 = rotl32(x1, 15); x1 ^= x0;
  x0 += x1; x1 = rotl32(x1, 26); x1 ^= x0;
  x0 += x1; x1 = rotl32(x1, 6);  x1 ^= x0;
  x0 += ks1; x1 += ks2 + 1u;
  x0 += x1; x1 = rotl32(x1, 17); x1 ^= x0;
  x0 += x1; x1 = rotl32(x1, 29); x1 ^= x0;
  x0 += x1; x1 = rotl32(x1, 16); x1 ^= x0;
  x0 += x1; x1 = rotl32(x1, 24); x1 ^= x0;
  x0 += ks2; x1 += ks0 + 2u;
  x0 += x1; x1 = rotl32(x1, 13); x1 ^= x0;
  x0 += x1; x1 = rotl32(x1, 15); x1 ^= x0;
  x0 += x1; x1 = rotl32(x1, 26); x1 ^= x0;
  x0 += x1; x1 = rotl32(x1, 6);  x1 ^= x0;
  x0 += ks0; x1 += ks1 + 3u;
  x0 += x1; x1 = rotl32(x1, 17); x1 ^= x0;
  x0 += x1; x1 = rotl32(x1, 29); x1 ^= x0;
  x0 += x1; x1 = rotl32(x1, 16); x1 ^= x0;
  x0 += x1; x1 = rotl32(x1, 24); x1 ^= x0;
  x0 += ks1; x1 += ks2 + 4u;
  x0 += x1; x1 = rotl32(x1, 13); x1 ^= x0;
  x0 += x1; x1 = rotl32(x1, 15); x1 ^= x0;
  x0 += x1; x1 = rotl32(x1, 26); x1 ^= x0;
  x0 += x1; x1 = rotl32(x1, 6);  x1 ^= x0;
  x0 += ks2; x1 += ks0 + 5u;
  U2 r; r.x = x0; r.y = x1; return r;
}

// jax_threefry_partitionable semantics (confirmed by v_raw stream match):
//  split(key, n)[i] = threefry(key, (0, i)) (both raw words)
//  random_bits32(key, shape)[i] = w0 ^ w1 of threefry(key, (0, i))
__device__ __forceinline__ U2 tf_subkey(U2 key, uint32_t i) { return tf2x32(key, 0u, i); }
__device__ __forceinline__ uint32_t tf_bits32(U2 key, uint32_t idx) {
  U2 r = tf2x32(key, 0u, idx);
  return r.x ^ r.y;
}

// bits -> [0,1) float exactly as jax.random.uniform does
__device__ __forceinline__ float unit_from_bits(uint32_t b) {
  uint32_t fb = (b >> 9) | 0x3f800000u;
  return __uint_as_float(fb) - 1.0f;
}

// f32 transcendentals via f64 (correctly rounded on cast; XLA polys ~1ulp away)
__device__ __forceinline__ float f32_log(float x)  { return (float)log((double)x); }
__device__ __forceinline__ float f32_exp(float x)  { return (float)exp((double)x); }
__device__ __forceinline__ float f32_log1p(float x){ return (float)log1p((double)x); }

// XLA ErfInv f32 (Giles polynomial) — exact op order, no FMA contraction
__device__ float erfinv32(float x) {
#pragma clang fp contract(off)
  float nxx = -(x * x);
  float w = -f32_log1p(nxx);
  float p;
  if (w < 5.0f) {
    w = w - 2.5f;
    p = 2.81022636e-08f;
    p = 3.43273939e-07f  + p * w;
    p = -3.5233877e-06f  + p * w;
    p = -4.39150654e-06f + p * w;
    p = 0.00021858087f   + p * w;
    p = -0.00125372503f  + p * w;
    p = -0.00417768164f  + p * w;
    p = 0.246640727f     + p * w;
    p = 1.50140941f      + p * w;
  } else {
    w = sqrtf(w) - 3.0f;
    p = -0.000200214257f;
    p = 0.000100950558f  + p * w;
    p = 0.00134934322f   + p * w;
    p = -0.00367342844f  + p * w;
    p = 0.00573950773f   + p * w;
    p = -0.0076224613f   + p * w;
    p = 0.00943887047f   + p * w;
    p = 1.00167406f      + p * w;
    p = 2.83297682f      + p * w;
  }
  return p * x;
}

// jax.random.normal(key, ()) from folded bits
__device__ __forceinline__ float normal_from_bits(uint32_t bits) {
#pragma clang fp contract(off)
  float u = unit_from_bits(bits);
  const float LO = -0.99999994f;          // nextafter(-1, 0) in f32
  float x = u * 2.0f + LO;                // (hi-lo) rounds to exactly 2.0f
  x = fmaxf(LO, x);
  return 1.4142135623730951f * erfinv32(x);
}

// jax _gamma_one(key, alpha=511.5, log_space=True): returns log(d) + log(V)
__device__ float loggamma_511_5(U2 gkey) {
#pragma clang fp contract(off)
  const float one_third = 1.0f / 3.0f;
  const float d = 511.5f - one_third;     // lax.sub(alpha, 1/3) in f32
  // Marsaglia-Tsang: c = 1/sqrt(9d). JAX: c = one_over_three / lax.sqrt(d).
  // (Round 1-2 bug: used (1/3)/sqrt(9d) = 3x too small -> loggamma spread
  //  compressed 3x -> w deviations scaled 1/3 -> absmax 0.033 signature.)
  const float c = one_third / sqrtf(d);
  // key, subkey = split(key): subkey -> u_boost (unused for alpha>=1)
  U2 key = tf_subkey(gkey, 0u);
  float V = 1.0f;
  for (int it = 0; it < 64; ++it) {
    U2 knext = tf_subkey(key, 0u);
    U2 xkey  = tf_subkey(key, 1u);
    U2 Ukey  = tf_subkey(key, 2u);
    float x, v;
    U2 xk = xkey;
    do {
      U2 xk_next = tf_subkey(xk, 0u);
      U2 nsub    = tf_subkey(xk, 1u);
      x = normal_from_bits(tf_bits32(nsub, 0u));
      v = 1.0f + x * c;
      xk = xk_next;
    } while (v <= 0.0f);
    float X = x * x;
    V = (v * v) * v;
    float U = unit_from_bits(tf_bits32(Ukey, 0u));
    float sq = 1.0f - 0.0331f * (X * X);
    bool cont;
    if (!(U >= sq)) {
      cont = false;
    } else {
      float logU = f32_log(U);
      float thr = X * 0.5f + d * ((1.0f - V) + f32_log(V));
      cont = (logU >= thr);
    }
    if (!cont) break;
    key = knext;
  }
  return f32_log(d) + f32_log(V);
}

// jax.random.beta(k1, 511.5, 511.5, (2048,)) element i — JAX's exact form:
//   ea = exp(lga - max); eb = exp(lgb - max); return ea / (ea + eb)
__device__ float beta_elem(U2 k1, uint32_t i) {
#pragma clang fp contract(off)
  U2 ka = tf_subkey(k1, 0u);
  U2 kb = tf_subkey(k1, 1u);
  U2 ga = tf_subkey(ka, i);
  U2 gb = tf_subkey(kb, i);
  float lga = loggamma_511_5(ga);
  float lgb = loggamma_511_5(gb);
  float m  = fmaxf(lga, lgb);
  float ea = f32_exp(lga - m);
  float eb = f32_exp(lgb - m);
  return ea / (ea + eb);
}

// ---------------------------------------------------------------------------
// Kernel 1: gather + sum over sequence
// ---------------------------------------------------------------------------
__global__ __launch_bounds__(128) void gather_sum_kernel(
    const int* __restrict__ add_tok, const int* __restrict__ rem_tok,
    const float* __restrict__ embed, float* __restrict__ sums) {
  int row = blockIdx.x;
  int which = blockIdx.y;
  const int* tok = (which == 0 ? add_tok : rem_tok) + (size_t)row * SEQ;
  __shared__ int t[SEQ];
  if (threadIdx.x < SEQ) t[threadIdx.x] = tok[threadIdx.x];
  __syncthreads();
  int c = threadIdx.x * 4;
  float4 acc = make_float4(0.f, 0.f, 0.f, 0.f);
  for (int s = 0; s < SEQ; ++s) {
    const float4 v = *(const float4*)&embed[(size_t)t[s] * EMB + c];
    acc.x += v.x; acc.y += v.y; acc.z += v.z; acc.w += v.w;
  }
  *(float4*)&sums[((size_t)which * NROWS + row) * EMB + c] = acc;
}

// ---------------------------------------------------------------------------
// Kernel 2: per-row vMF radial weight w (Wood sampler) + trand
// ---------------------------------------------------------------------------
__global__ void w_kernel(float* __restrict__ w_out, float* __restrict__ trand_out) {
#pragma clang fp contract(off)
  int i = blockIdx.x * blockDim.x + threadIdx.x;
  if (i >= NROWS) return;
  U2 key42; key42.x = 0u; key42.y = 42u;
  U2 kw = tf_subkey(key42, 0u);
  U2 kt = tf_subkey(key42, 2u);

  trand_out[i] = unit_from_bits(tf_bits32(kt, (uint32_t)i)) * 0.1f;

  const double kappa_d = 80.0, dimr_d = 1023.0;
  const double b_d = dimr_d / (sqrt(4.0 * kappa_d * kappa_d + dimr_d * dimr_d) + 2.0 * kappa_d);
  const double x_d = (1.0 - b_d) / (1.0 + b_d);
  const double c_d = kappa_d * x_d + dimr_d * log(1.0 - x_d * x_d);
  const float bf = (float)b_d, xf = (float)x_d, cf = (float)c_d;
  const float b1p = 1.0f + bf, b1m = 1.0f - bf;

  U2 K = kw;
  float w = 0.0f;
  for (int t = 0; t < 64; ++t) {
    U2 Kn = tf_subkey(K, 0u);
    U2 k1 = tf_subkey(K, 1u);
    U2 k2 = tf_subkey(K, 2u);
    float z = beta_elem(k1, (uint32_t)i);
    float wn = (1.0f - b1p * z) / (1.0f - b1m * z);
    float u = unit_from_bits(tf_bits32(k2, (uint32_t)i));
    float lhs = (80.0f * wn + 1023.0f * f32_log(1.0f - xf * wn)) - cf;
    float rhs = f32_log(u);
    if (lhs >= rhs) { w = wn; break; }
    K = Kn;
  }
  w_out[i] = w;
}

// ---------------------------------------------------------------------------
// Kernel 3: fused per-row GEMM (combined = sums @ W^T) + finalize
// ---------------------------------------------------------------------------
__device__ __forceinline__ float block_reduce_sum256(float v, float* red) {
#pragma unroll
  for (int off = 32; off > 0; off >>= 1) v += __shfl_down(v, off, 64);
  if ((threadIdx.x & 63) == 0) red[threadIdx.x >> 6] = v;
  __syncthreads();
  float s = red[0] + red[1] + red[2] + red[3];
  __syncthreads();
  return s;
}

__global__ __launch_bounds__(256) void fused_row_kernel(
    const float* __restrict__ sums, const float* __restrict__ W,
    const float* __restrict__ w_arr, const float* __restrict__ trand,
    float* __restrict__ out) {
  __shared__ float Aad[EMB];
  __shared__ float Arm[EMB];
  __shared__ float red[4];
  int r = blockIdx.x, tid = threadIdx.x;

  for (int k = tid; k < EMB; k += 256) {
    Aad[k] = sums[(size_t)r * EMB + k];
    Arm[k] = sums[((size_t)NROWS + r) * EMB + k];
  }
  __syncthreads();

  float mu[4];
#pragma unroll
  for (int q = 0; q < 4; ++q) {
    int j = tid + q * 256;
    const float* As = (j < 512) ? Aad : Arm;
    const float4* Wv = (const float4*)&W[(size_t)(j & 511) * EMB];
    float acc = 0.f;
    for (int k4 = 0; k4 < EMB / 4; ++k4) {
      float4 wv = Wv[k4];
      float4 av = *(const float4*)&As[k4 * 4];
      acc += av.x * wv.x + av.y * wv.y + av.z * wv.z + av.w * wv.w;
    }
    mu[q] = acc;
  }

  {
#pragma clang fp contract(off)
    U2 key42; key42.x = 0u; key42.y = 42u;
    U2 kv = tf_subkey(key42, 1u);
    float vr[4];
#pragma unroll
    for (int q = 0; q < 4; ++q) {
      int j = tid + q * 256;
      vr[q] = normal_from_bits(tf_bits32(kv, (uint32_t)(r * HID + j)));
    }
    float ss = mu[0]*mu[0] + mu[1]*mu[1] + mu[2]*mu[2] + mu[3]*mu[3];
    ss = block_reduce_sum256(ss, red);
    float munorm = sqrtf(ss);
    float safe = fmaxf(munorm, 1e-20f);
    float muh[4];
#pragma unroll
    for (int q = 0; q < 4; ++q) muh[q] = mu[q] / safe;
    float pp = muh[0]*vr[0] + muh[1]*vr[1] + muh[2]*vr[2] + muh[3]*vr[3];
    pp = block_reduce_sum256(pp, red);
    float ortho[4];
#pragma unroll
    for (int q = 0; q < 4; ++q) ortho[q] = vr[q] - muh[q] * pp;
    float os = ortho[0]*ortho[0] + ortho[1]*ortho[1] + ortho[2]*ortho[2] + ortho[3]*ortho[3];
    os = block_reduce_sum256(os, red);
    float on = sqrtf(os);

    float w = w_arr[r];
    float sqw = sqrtf(1.0f - w * w);
    float munoise = fminf(fmaxf(munorm, 0.0f), 13.9f) + trand[r];
#pragma unroll
    for (int q = 0; q < 4; ++q) {
      int j = tid + q * 256;
      float v = ortho[q] / on;
      out[(size_t)r * HID + j] = (v * sqw + muh[q] * w) * munoise;
    }
  }
}

// ---------------------------------------------------------------------------
extern "C" void kernel_launch(void* const* d_in, const int* in_sizes, int n_in,
                              void* d_out, int out_size, void* d_ws, size_t ws_size,
                              hipStream_t stream) {
  const int*   add_tok = (const int*)d_in[0];
  const int*   rem_tok = (const int*)d_in[1];
  const float* embed   = (const float*)d_in[2];
  const float* W       = (const float*)d_in[3];
  float* out = (float*)d_out;

  float* ws     = (float*)d_ws;
  float* w_arr  = ws;                       // 2048
  float* tr_arr = ws + NROWS;               // 2048
  float* sums   = ws + 2 * NROWS;           // 2 * 2048 * 512

  gather_sum_kernel<<<dim3(NROWS, 2), 128, 0, stream>>>(add_tok, rem_tok, embed, sums);
  w_kernel<<<(NROWS + 255) / 256, 256, 0, stream>>>(w_arr, tr_arr);
  fused_row_kernel<<<NROWS, 256, 0, stream>>>(sums, W, w_arr, tr_arr, out);
}

// Round 4
// 220.351 us; speedup vs baseline: 2.8047x; 2.8047x over previous
//
#include <hip/hip_runtime.h>
#include <stdint.h>
#include <math.h>

// Problem constants
#define NROWS 2048
#define SEQ   128
#define EMB   512
#define HID   1024   // output cols per row

// ---------------------------------------------------------------------------
// threefry2x32 (JAX PRNG), exact
// ---------------------------------------------------------------------------
struct U2 { uint32_t x, y; };

__device__ __forceinline__ uint32_t rotl32(uint32_t v, int r) {
  return (v << r) | (v >> (32 - r));
}

__device__ __forceinline__ U2 tf2x32(U2 key, uint32_t x0, uint32_t x1) {
  uint32_t ks0 = key.x, ks1 = key.y;
  uint32_t ks2 = ks0 ^ ks1 ^ 0x1BD11BDAu;
  x0 += ks0; x1 += ks1;
  x0 += x1; x1 = rotl32(x1, 13); x1 ^= x0;
  x0 += x1; x1 = rotl32(x1, 15); x1 ^= x0;
  x0 += x1; x1 = rotl32(x1, 26); x1 ^= x0;
  x0 += x1; x1 = rotl32(x1, 6);  x1 ^= x0;
  x0 += ks1; x1 += ks2 + 1u;
  x0 += x1; x1 = rotl32(x1, 17); x1 ^= x0;
  x0 += x1; x1 = rotl32(x1, 29); x1 ^= x0;
  x0 += x1; x1 = rotl32(x1, 16); x1 ^= x0;
  x0 += x1; x1 = rotl32(x1, 24); x1 ^= x0;
  x0 += ks2; x1 += ks0 + 2u;
  x0 += x1; x1 = rotl32(x1, 13); x1 ^= x0;
  x0 += x1; x1 = rotl32(x1, 15); x1 ^= x0;
  x0 += x1; x1 = rotl32(x1, 26); x1 ^= x0;
  x0 += x1; x1 = rotl32(x1, 6);  x1 ^= x0;
  x0 += ks0; x1 += ks1 + 3u;
  x0 += x1; x1 = rotl32(x1, 17); x1 ^= x0;
  x0 += x1; x1 = rotl32(x1, 29); x1 ^= x0;
  x0 += x1; x1 = rotl32(x1, 16); x1 ^= x0;
  x0 += x1; x1 = rotl32(x1, 24); x1 ^= x0;
  x0 += ks1; x1 += ks2 + 4u;
  x0 += x1; x1 = rotl32(x1, 13); x1 ^= x0;
  x0 += x1; x1 = rotl32(x1, 15); x1 ^= x0;
  x0 += x1; x1 = rotl32(x1, 26); x1 ^= x0;
  x0 += x1; x1 = rotl32(x1, 6);  x1 ^= x0;
  x0 += ks2; x1 += ks0 + 5u;
  U2 r; r.x = x0; r.y = x1; return r;
}

__device__ __forceinline__ U2 tf_subkey(U2 key, uint32_t i) { return tf2x32(key, 0u, i); }
__device__ __forceinline__ uint32_t tf_bits32(U2 key, uint32_t idx) {
  U2 r = tf2x32(key, 0u, idx);
  return r.x ^ r.y;
}

__device__ __forceinline__ float unit_from_bits(uint32_t b) {
  uint32_t fb = (b >> 9) | 0x3f800000u;
  return __uint_as_float(fb) - 1.0f;
}

__device__ __forceinline__ float f32_log(float x)  { return (float)log((double)x); }
__device__ __forceinline__ float f32_exp(float x)  { return (float)exp((double)x); }
__device__ __forceinline__ float f32_log1p(float x){ return (float)log1p((double)x); }

// XLA ErfInv f32 (Giles polynomial) — exact op order, no FMA contraction
__device__ float erfinv32(float x) {
#pragma clang fp contract(off)
  float nxx = -(x * x);
  float w = -f32_log1p(nxx);
  float p;
  if (w < 5.0f) {
    w = w - 2.5f;
    p = 2.81022636e-08f;
    p = 3.43273939e-07f  + p * w;
    p = -3.5233877e-06f  + p * w;
    p = -4.39150654e-06f + p * w;
    p = 0.00021858087f   + p * w;
    p = -0.00125372503f  + p * w;
    p = -0.00417768164f  + p * w;
    p = 0.246640727f     + p * w;
    p = 1.50140941f      + p * w;
  } else {
    w = sqrtf(w) - 3.0f;
    p = -0.000200214257f;
    p = 0.000100950558f  + p * w;
    p = 0.00134934322f   + p * w;
    p = -0.00367342844f  + p * w;
    p = 0.00573950773f   + p * w;
    p = -0.0076224613f   + p * w;
    p = 0.00943887047f   + p * w;
    p = 1.00167406f      + p * w;
    p = 2.83297682f      + p * w;
  }
  return p * x;
}

__device__ __forceinline__ float normal_from_bits(uint32_t bits) {
#pragma clang fp contract(off)
  float u = unit_from_bits(bits);
  const float LO = -0.99999994f;
  float x = u * 2.0f + LO;
  x = fmaxf(LO, x);
  return 1.4142135623730951f * erfinv32(x);
}

// jax _gamma_one(key, alpha=511.5, log_space=True): returns log(d) + log(V)
__device__ float loggamma_511_5(U2 gkey) {
#pragma clang fp contract(off)
  const float one_third = 1.0f / 3.0f;
  const float d = 511.5f - one_third;
  const float c = one_third / sqrtf(d);   // JAX: one_over_three / lax.sqrt(d)
  U2 key = tf_subkey(gkey, 0u);           // boost subkey unused for alpha>=1
  float V = 1.0f;
  for (int it = 0; it < 64; ++it) {
    U2 knext = tf_subkey(key, 0u);
    U2 xkey  = tf_subkey(key, 1u);
    U2 Ukey  = tf_subkey(key, 2u);
    float x, v;
    U2 xk = xkey;
    do {
      U2 xk_next = tf_subkey(xk, 0u);
      U2 nsub    = tf_subkey(xk, 1u);
      x = normal_from_bits(tf_bits32(nsub, 0u));
      v = 1.0f + x * c;
      xk = xk_next;
    } while (v <= 0.0f);
    float X = x * x;
    V = (v * v) * v;
    float U = unit_from_bits(tf_bits32(Ukey, 0u));
    float sq = 1.0f - 0.0331f * (X * X);
    bool cont;
    if (!(U >= sq)) {
      cont = false;
    } else {
      float logU = f32_log(U);
      float thr = X * 0.5f + d * ((1.0f - V) + f32_log(V));
      cont = (logU >= thr);
    }
    if (!cont) break;
    key = knext;
  }
  return f32_log(d) + f32_log(V);
}

__device__ float beta_elem(U2 k1, uint32_t i) {
#pragma clang fp contract(off)
  U2 ka = tf_subkey(k1, 0u);
  U2 kb = tf_subkey(k1, 1u);
  U2 ga = tf_subkey(ka, i);
  U2 gb = tf_subkey(kb, i);
  float lga = loggamma_511_5(ga);
  float lgb = loggamma_511_5(gb);
  float m  = fmaxf(lga, lgb);
  float ea = f32_exp(lga - m);
  float eb = f32_exp(lgb - m);
  return ea / (ea + eb);
}

// ---------------------------------------------------------------------------
// Kernel 1: gather + sum over sequence
// ---------------------------------------------------------------------------
__global__ __launch_bounds__(128) void gather_sum_kernel(
    const int* __restrict__ add_tok, const int* __restrict__ rem_tok,
    const float* __restrict__ embed, float* __restrict__ sums) {
  int row = blockIdx.x;
  int which = blockIdx.y;
  const int* tok = (which == 0 ? add_tok : rem_tok) + (size_t)row * SEQ;
  __shared__ int t[SEQ];
  if (threadIdx.x < SEQ) t[threadIdx.x] = tok[threadIdx.x];
  __syncthreads();
  int c = threadIdx.x * 4;
  float4 acc = make_float4(0.f, 0.f, 0.f, 0.f);
  for (int s = 0; s < SEQ; ++s) {
    const float4 v = *(const float4*)&embed[(size_t)t[s] * EMB + c];
    acc.x += v.x; acc.y += v.y; acc.z += v.z; acc.w += v.w;
  }
  *(float4*)&sums[((size_t)which * NROWS + row) * EMB + c] = acc;
}

// ---------------------------------------------------------------------------
// Kernel 2: per-row vMF radial weight w (Wood sampler) + trand
// ---------------------------------------------------------------------------
__global__ void w_kernel(float* __restrict__ w_out, float* __restrict__ trand_out) {
#pragma clang fp contract(off)
  int i = blockIdx.x * blockDim.x + threadIdx.x;
  if (i >= NROWS) return;
  U2 key42; key42.x = 0u; key42.y = 42u;
  U2 kw = tf_subkey(key42, 0u);
  U2 kt = tf_subkey(key42, 2u);

  trand_out[i] = unit_from_bits(tf_bits32(kt, (uint32_t)i)) * 0.1f;

  const double kappa_d = 80.0, dimr_d = 1023.0;
  const double b_d = dimr_d / (sqrt(4.0 * kappa_d * kappa_d + dimr_d * dimr_d) + 2.0 * kappa_d);
  const double x_d = (1.0 - b_d) / (1.0 + b_d);
  const double c_d = kappa_d * x_d + dimr_d * log(1.0 - x_d * x_d);
  const float bf = (float)b_d, xf = (float)x_d, cf = (float)c_d;
  const float b1p = 1.0f + bf, b1m = 1.0f - bf;

  U2 K = kw;
  float w = 0.0f;
  for (int t = 0; t < 64; ++t) {
    U2 Kn = tf_subkey(K, 0u);
    U2 k1 = tf_subkey(K, 1u);
    U2 k2 = tf_subkey(K, 2u);
    float z = beta_elem(k1, (uint32_t)i);
    float wn = (1.0f - b1p * z) / (1.0f - b1m * z);
    float u = unit_from_bits(tf_bits32(k2, (uint32_t)i));
    float lhs = (80.0f * wn + 1023.0f * f32_log(1.0f - xf * wn)) - cf;
    float rhs = f32_log(u);
    if (lhs >= rhs) { w = wn; break; }
    K = Kn;
  }
  w_out[i] = w;
}

// ---------------------------------------------------------------------------
// Kernel 3: tiled f32 GEMM  combined[r][c] = dot(sums[c<512?add:rem][r], W[c&511])
// 64x64 tile, BK=16, 256 threads, 4x4 acc/thread. Writes combined into d_out.
// ---------------------------------------------------------------------------
__global__ __launch_bounds__(256) void gemm_kernel(
    const float* __restrict__ sums, const float* __restrict__ W,
    float* __restrict__ out) {
  __shared__ float As[16][64];
  __shared__ float Bs[16][64];
  int r0 = blockIdx.x * 64;
  int c0 = blockIdx.y * 64;
  const float* A = sums + ((c0 < 512) ? 0 : (size_t)NROWS * EMB);
  int wc0 = c0 & 511;
  int tid = threadIdx.x;
  int tx = tid & 15, ty = tid >> 4;
  int lr = tid >> 2, lk = (tid & 3) * 4;
  float acc[4][4] = {};
  for (int k0 = 0; k0 < EMB; k0 += 16) {
    float4 av = *(const float4*)&A[(size_t)(r0 + lr) * EMB + k0 + lk];
    float4 bv = *(const float4*)&W[(size_t)(wc0 + lr) * EMB + k0 + lk];
    __syncthreads();
    As[lk + 0][lr] = av.x; As[lk + 1][lr] = av.y; As[lk + 2][lr] = av.z; As[lk + 3][lr] = av.w;
    Bs[lk + 0][lr] = bv.x; Bs[lk + 1][lr] = bv.y; Bs[lk + 2][lr] = bv.z; Bs[lk + 3][lr] = bv.w;
    __syncthreads();
#pragma unroll
    for (int kk = 0; kk < 16; ++kk) {
      float a[4], b[4];
#pragma unroll
      for (int m = 0; m < 4; ++m) a[m] = As[kk][ty * 4 + m];
#pragma unroll
      for (int n = 0; n < 4; ++n) b[n] = Bs[kk][tx * 4 + n];
#pragma unroll
      for (int m = 0; m < 4; ++m)
#pragma unroll
        for (int n = 0; n < 4; ++n) acc[m][n] += a[m] * b[n];
    }
  }
#pragma unroll
  for (int m = 0; m < 4; ++m)
#pragma unroll
    for (int n = 0; n < 4; ++n)
      out[(size_t)(r0 + ty * 4 + m) * HID + c0 + tx * 4 + n] = acc[m][n];
}

// ---------------------------------------------------------------------------
// Kernel 4: per-row finalize — reads combined row from d_out, rewrites in place
// ---------------------------------------------------------------------------
__device__ __forceinline__ float block_reduce_sum256(float v, float* red) {
#pragma unroll
  for (int off = 32; off > 0; off >>= 1) v += __shfl_down(v, off, 64);
  if ((threadIdx.x & 63) == 0) red[threadIdx.x >> 6] = v;
  __syncthreads();
  float s = red[0] + red[1] + red[2] + red[3];
  __syncthreads();
  return s;
}

__global__ __launch_bounds__(256) void finalize_kernel(
    const float* __restrict__ w_arr, const float* __restrict__ trand,
    float* __restrict__ out) {
#pragma clang fp contract(off)
  __shared__ float red[4];
  int r = blockIdx.x, tid = threadIdx.x;
  U2 key42; key42.x = 0u; key42.y = 42u;
  U2 kv = tf_subkey(key42, 1u);

  float mu[4], vr[4];
#pragma unroll
  for (int q = 0; q < 4; ++q) {
    int j = tid + q * 256;
    mu[q] = out[(size_t)r * HID + j];
    vr[q] = normal_from_bits(tf_bits32(kv, (uint32_t)(r * HID + j)));
  }
  float ss = mu[0]*mu[0] + mu[1]*mu[1] + mu[2]*mu[2] + mu[3]*mu[3];
  ss = block_reduce_sum256(ss, red);
  float munorm = sqrtf(ss);
  float safe = fmaxf(munorm, 1e-20f);
  float muh[4];
#pragma unroll
  for (int q = 0; q < 4; ++q) muh[q] = mu[q] / safe;
  float pp = muh[0]*vr[0] + muh[1]*vr[1] + muh[2]*vr[2] + muh[3]*vr[3];
  pp = block_reduce_sum256(pp, red);
  float ortho[4];
#pragma unroll
  for (int q = 0; q < 4; ++q) ortho[q] = vr[q] - muh[q] * pp;
  float os = ortho[0]*ortho[0] + ortho[1]*ortho[1] + ortho[2]*ortho[2] + ortho[3]*ortho[3];
  os = block_reduce_sum256(os, red);
  float on = sqrtf(os);

  float w = w_arr[r];
  float sqw = sqrtf(1.0f - w * w);
  float munoise = fminf(fmaxf(munorm, 0.0f), 13.9f) + trand[r];
#pragma unroll
  for (int q = 0; q < 4; ++q) {
    int j = tid + q * 256;
    float v = ortho[q] / on;
    out[(size_t)r * HID + j] = (v * sqw + muh[q] * w) * munoise;
  }
}

// ---------------------------------------------------------------------------
extern "C" void kernel_launch(void* const* d_in, const int* in_sizes, int n_in,
                              void* d_out, int out_size, void* d_ws, size_t ws_size,
                              hipStream_t stream) {
  const int*   add_tok = (const int*)d_in[0];
  const int*   rem_tok = (const int*)d_in[1];
  const float* embed   = (const float*)d_in[2];
  const float* W       = (const float*)d_in[3];
  float* out = (float*)d_out;

  // ws: 8.02 MB total (combined lives in d_out)
  float* ws     = (float*)d_ws;
  float* w_arr  = ws;                       // 2048
  float* tr_arr = ws + NROWS;               // 2048
  float* sums   = ws + 2 * NROWS;           // 2 * 2048 * 512

  gather_sum_kernel<<<dim3(NROWS, 2), 128, 0, stream>>>(add_tok, rem_tok, embed, sums);
  w_kernel<<<(NROWS + 255) / 256, 256, 0, stream>>>(w_arr, tr_arr);
  gemm_kernel<<<dim3(NROWS / 64, HID / 64), 256, 0, stream>>>(sums, W, out);
  finalize_kernel<<<NROWS, 256, 0, stream>>>(w_arr, tr_arr, out);
}